// Round 11
// baseline (220.532 us; speedup 1.0000x reference)
//
#include <hip/hip_runtime.h>
#include <math.h>

// ISTFT via TWO-FOR-ONE register-resident inverse FFT + LDS overlap-add.
//   B=16, T=2048, 513 bins, FFT=1024, HOP=256, out = 16 x 525056 (= 2051*256).
//   Two frames at once: G[k] = Ya[k] + i*Yb[k] (hermitian-extended, DC/Nyquist
//   imag zeroed) -> IFFT_1024(G) = x_a + i*x_b in ONE complex FFT.
//   IFFT_1024 = 16(in-lane radix-4^2) x 64(cross-lane DIF, s = bitrev6(lane)):
//     u_l[m] = sum_q G[l+64q] W16^{mq}   (in-lane 16-pt, m = 0..15)
//     v_l[m] = u_l[m] * P^{l m}, P = e^{2pi i l/1024}   (serial P-chain)
//     z[16s+m] = sum_l v_l[m] W64^{sl}   (6 DIF stages: permlane32/16, DPP, swz)
//   Lane ends holding 16 CONSECUTIVE samples n0..n0+15 (n0=16*bitrev6(lane)):
//   one window weight per sample serves BOTH frames (.x -> a, .y -> b).
// R11: halves VALU work per frame vs R10 (no pack stage, FFT shared by 2 frames).

#define BATCH  16
#define TFR    2048
#define NB     513
#define HOP    256
#define OUTLEN 525056
#define TROWS  2051
#define OWN    32
#define NBLK   65                         // ceil(2051/32)
#define OLALEN (OWN * HOP)                // 8192
#define OLAPAD (OLALEN + OLALEN / 16)     // 8704 floats = 34.8 KB

#define NTHR   512
#define NWAVE  8

#define PIDX(n) ((n) + ((n) >> 4))

#define TWO_PI 6.2831853071795864f
#define WSCALE 8.456302966727588e-4f      // (sqrt(3)/2) / 1024

__device__ __forceinline__ float2 cadd(float2 a, float2 b){ return make_float2(a.x+b.x, a.y+b.y); }
__device__ __forceinline__ float2 csub(float2 a, float2 b){ return make_float2(a.x-b.x, a.y-b.y); }
__device__ __forceinline__ float2 cmul(float2 a, float2 b){ return make_float2(a.x*b.x - a.y*b.y, a.x*b.y + a.y*b.x); }
__device__ __forceinline__ float2 cmuli(float2 a){ return make_float2(-a.y, a.x); }      // i*a
__device__ __forceinline__ float2 cmulni(float2 a){ return make_float2(a.y, -a.x); }     // -i*a

#if __has_builtin(__builtin_amdgcn_permlane32_swap)
#define HAVE_PL32 1
__device__ __forceinline__ float plsel32(float v, bool pick0) {
    auto r = __builtin_amdgcn_permlane32_swap(
        __builtin_bit_cast(int, v), __builtin_bit_cast(int, v), false, false);
    return __builtin_bit_cast(float, pick0 ? r[0] : r[1]);
}
#else
#define HAVE_PL32 0
#endif

#if __has_builtin(__builtin_amdgcn_permlane16_swap)
#define HAVE_PL16 1
__device__ __forceinline__ float plsel16(float v, bool pick0) {
    auto r = __builtin_amdgcn_permlane16_swap(
        __builtin_bit_cast(int, v), __builtin_bit_cast(int, v), false, false);
    return __builtin_bit_cast(float, pick0 ? r[0] : r[1]);
}
#else
#define HAVE_PL16 0
#endif

// DPP xor within 16-lane rows: xor1 = quad_perm{1,0,3,2}=0xB1,
// xor2 = quad_perm{2,3,0,1}=0x4E, xor8 = row_ror:8 = 0x128.
template<int CTRL>
__device__ __forceinline__ float dppf(float v) {
    return __builtin_bit_cast(float,
        __builtin_amdgcn_update_dpp(0, __builtin_bit_cast(int, v), CTRL, 0xF, 0xF, true));
}
// ds_swizzle BitMode xor4: offset = (4<<10)|0x1F
__device__ __forceinline__ float swz4(float v) {
    return __builtin_bit_cast(float,
        __builtin_amdgcn_ds_swizzle(__builtin_bit_cast(int, v), 0x101F));
}

// butterfly: lo lanes -> u+p ; hi lanes -> (u-p) * e^{2pi i l/(2h)}
__device__ __forceinline__ float2 bstep(float2 u, float2 p, bool hi, float2 W) {
    const float2 s = cadd(u, p);
    const float2 d = cmul(csub(u, p), W);
    return hi ? d : s;
}

// window literals cos/sin(2pi j/1024), j = 0..15
__device__ __constant__ const float CWT[16] = {
    1.f, 0.9999811752826011f, 0.9999247018391445f, 0.9998305817958234f,
    0.9996988186962042f, 0.9995294175010931f, 0.9993223845883495f, 0.9990777277526454f,
    0.9987954562051724f, 0.9984755805732948f, 0.9981181129001492f, 0.9977230666441916f,
    0.9972904566786902f, 0.9968202992911657f, 0.9963126121827780f, 0.9957674144676598f };
__device__ __constant__ const float SWT[16] = {
    0.f, 0.0061358846491545f, 0.0122715382857199f, 0.0184067299058048f,
    0.0245412285229123f, 0.0306748031766366f, 0.0368072229413588f, 0.0429382569349408f,
    0.0490676743274180f, 0.0551952443496899f, 0.0613207363022086f, 0.0674439195636641f,
    0.0735645635996674f, 0.0796824379714301f, 0.0857973123444399f, 0.0919089564971327f };

// slot of u[m] after in-place radix-4^2: sl(m) = 4*(m&3) + (m>>2)
#define SL0 0
#define SLS {0,4,8,12,1,5,9,13,2,6,10,14,3,7,11,15}

__global__ __launch_bounds__(NTHR)
void istft_rfft2(const float2* __restrict__ stfts, float* __restrict__ out)
{
    __shared__ float ola[OLAPAD];

    const int tid  = threadIdx.x;
    const int lane = tid & 63;
    const int wave = tid >> 6;

    const int b  = blockIdx.x / NBLK;
    const int ib = blockIdx.x - b * NBLK;
    const int T0 = ib * OWN;

    for (int i = tid; i < OLAPAD; i += NTHR) ola[i] = 0.f;

    // ---- base roots; every twiddle derives from these ----
    float2 P, V;
    { float s, c; sincosf(TWO_PI * (float)lane * (1.0f/1024.0f), &s, &c); P = make_float2(c, s); }
    const int brl = ((lane & 1) << 5) | ((lane & 2) << 3) | ((lane & 4) << 1)
                  | ((lane & 8) >> 1) | ((lane & 16) >> 3) | ((lane & 32) >> 5);
    const int n0 = brl * 16;
    { float s, c; sincosf(TWO_PI * (float)n0 * (1.0f/1024.0f), &s, &c); V = make_float2(c, s); }

    // stage twiddles B_{2h} = e^{2pi i l / (2h)} via repeated squaring of P
    const float2 Qt  = cmul(P, P);
    const float2 P4t = cmul(Qt, Qt);
    const float2 P8t = cmul(P4t, P4t);
    const float2 B64 = cmul(P8t, P8t);    // e^{2pi i l/64}
    const float2 B32 = cmul(B64, B64);
    const float2 B16 = cmul(B32, B32);
    const float2 B8c = cmul(B16, B16);
    const float2 B4c = cmul(B8c, B8c);

#if HAVE_PL32
    bool pick32;
    { auto pr = __builtin_amdgcn_permlane32_swap(lane, lane, false, false);
      pick32 = (pr[0] == (lane ^ 32)); }
#endif
#if HAVE_PL16
    bool pick16;
    { auto pr = __builtin_amdgcn_permlane16_swap(lane, lane, false, false);
      pick16 = (pr[0] == (lane ^ 16)); }
#endif
    const bool hi32 = lane >= 32;
    const bool hi16 = (lane & 16) != 0;
    const bool hi8  = (lane & 8)  != 0;
    const bool hi4  = (lane & 4)  != 0;
    const bool hi2  = (lane & 2)  != 0;
    const bool hi1  = (lane & 1)  != 0;

    __syncthreads();   // ola zeroed

    const int tmin   = (T0 - 3 > 0) ? T0 - 3 : 0;
    const int tmax   = (T0 + OWN - 1 < TFR - 1) ? T0 + OWN - 1 : TFR - 1;
    const int npairs = (tmax - tmin + 2) >> 1;

    static constexpr int SL[16] = SLS;

    for (int pi = wave; pi < npairs; pi += NWAVE) {
        const int  ta = tmin + 2 * pi;
        const int  tb = ta + 1;
        const bool vb = (tb <= tmax);

        const float2* Ga = stfts + (size_t)(b * TFR + ta) * NB;
        const float2* Gb = stfts + (size_t)(b * TFR + (vb ? tb : ta)) * NB;

        // ascending (k = lane+64q, q=0..7) and descending mirror
        // (mi = 512-64r-lane, for k = 512+64r+lane) loads — all coalesced.
        float2 Aa[8], Ab[8], Da[8], Db[8];
        #pragma unroll
        for (int r = 0; r < 8; ++r) { Aa[r] = Ga[lane + 64 * r];       Ab[r] = Gb[lane + 64 * r]; }
        #pragma unroll
        for (int r = 0; r < 8; ++r) { Da[r] = Ga[512 - 64 * r - lane]; Db[r] = Gb[512 - 64 * r - lane]; }

        // G[k] = Ya[k] + i*Yb[k]; upper half via conj mirror.
        float2 z[16];
        #pragma unroll
        for (int q = 0; q < 8; ++q) {            // k = lane+64q <= 511
            float ya = Aa[q].y, yb = Ab[q].y;
            if (lane == 0 && q == 0) { ya = 0.f; yb = 0.f; }        // DC imag -> 0
            z[q] = make_float2(Aa[q].x - yb, ya + Ab[q].x);
        }
        #pragma unroll
        for (int r = 0; r < 8; ++r) {            // k = 512+64r+lane: conj(Y[1024-k])
            float may = Da[r].y, mby = Db[r].y;
            if (lane == 0 && r == 0) { may = 0.f; mby = 0.f; }      // Nyquist imag -> 0
            z[8 + r] = make_float2(Da[r].x + mby, Db[r].x - may);
        }

        // ---- in-lane 16-pt inverse DFT (radix-4^2, in place) ----
        // layer 1: 4-pt over q1 on groups {q0, q0+4, q0+8, q0+12}
        #pragma unroll
        for (int q0 = 0; q0 < 4; ++q0) {
            const float2 a = z[q0], bb = z[q0+4], c = z[q0+8], d = z[q0+12];
            const float2 s0 = cadd(a, c), d0 = csub(a, c);
            const float2 s1 = cadd(bb, d), d1 = csub(bb, d);
            z[q0]      = cadd(s0, s1);
            z[q0 + 4]  = cadd(d0, cmuli(d1));
            z[q0 + 8]  = csub(s0, s1);
            z[q0 + 12] = cadd(d0, cmulni(d1));
        }
        // twiddles W16^{q0*m0} at slot q0+4*m0 (inverse sign: W16 = e^{+2pi i/16})
        {
            const float2 W1 = make_float2(0.9238795325112867f, 0.3826834323650898f);
            const float2 W2 = make_float2(0.7071067811865476f, 0.7071067811865476f);
            const float2 W3 = make_float2(0.3826834323650898f, 0.9238795325112867f);
            const float2 W6 = make_float2(-0.7071067811865476f, 0.7071067811865476f);
            const float2 W9 = make_float2(-0.9238795325112867f, -0.3826834323650898f);
            z[5]  = cmul(z[5],  W1);  z[6]  = cmul(z[6],  W2);  z[7]  = cmul(z[7],  W3);
            z[9]  = cmul(z[9],  W2);  z[10] = cmuli(z[10]);     z[11] = cmul(z[11], W6);
            z[13] = cmul(z[13], W3);  z[14] = cmul(z[14], W6);  z[15] = cmul(z[15], W9);
        }
        // layer 2: 4-pt over q0 on groups {4m0 .. 4m0+3}; u[m0+4m1] -> slot 4m0+m1
        #pragma unroll
        for (int m0 = 0; m0 < 4; ++m0) {
            const float2 a = z[4*m0], bb = z[4*m0+1], c = z[4*m0+2], d = z[4*m0+3];
            const float2 s0 = cadd(a, c), d0 = csub(a, c);
            const float2 s1 = cadd(bb, d), d1 = csub(bb, d);
            z[4*m0]     = cadd(s0, s1);
            z[4*m0 + 1] = cadd(d0, cmuli(d1));
            z[4*m0 + 2] = csub(s0, s1);
            z[4*m0 + 3] = cadd(d0, cmulni(d1));
        }
        // m-twiddle: u[m] *= P^m (serial P-chain, slots via SL)
        {
            float2 tw = P;
            z[SL[1]] = cmul(z[SL[1]], tw);
            #pragma unroll
            for (int m = 2; m < 16; ++m) {
                tw = cmul(tw, P);
                z[SL[m]] = cmul(z[SL[m]], tw);
            }
        }

        // ---- 64-pt cross-lane inverse DFT, 6 DIF stages ----
        #pragma unroll
        for (int m = 0; m < 16; ++m) {        // h=32: permlane32_swap (VALU)
            float2 p;
#if HAVE_PL32
            p = make_float2(plsel32(z[m].x, pick32), plsel32(z[m].y, pick32));
#else
            p = make_float2(__shfl_xor(z[m].x, 32), __shfl_xor(z[m].y, 32));
#endif
            z[m] = bstep(z[m], p, hi32, B64);
        }
        #pragma unroll
        for (int m = 0; m < 16; ++m) {        // h=16: permlane16_swap (VALU)
            float2 p;
#if HAVE_PL16
            p = make_float2(plsel16(z[m].x, pick16), plsel16(z[m].y, pick16));
#else
            p = make_float2(__shfl_xor(z[m].x, 16), __shfl_xor(z[m].y, 16));
#endif
            z[m] = bstep(z[m], p, hi16, B32);
        }
        #pragma unroll
        for (int m = 0; m < 16; ++m) {        // h=8: DPP row_ror:8 (VALU)
            const float2 p = make_float2(dppf<0x128>(z[m].x), dppf<0x128>(z[m].y));
            z[m] = bstep(z[m], p, hi8, B16);
        }
        #pragma unroll
        for (int m = 0; m < 16; ++m) {        // h=4: ds_swizzle xor4 (DS)
            const float2 p = make_float2(swz4(z[m].x), swz4(z[m].y));
            z[m] = bstep(z[m], p, hi4, B8c);
        }
        #pragma unroll
        for (int m = 0; m < 16; ++m) {        // h=2: DPP quad_perm xor2 (VALU)
            const float2 p = make_float2(dppf<0x4E>(z[m].x), dppf<0x4E>(z[m].y));
            z[m] = bstep(z[m], p, hi2, B4c);
        }
        #pragma unroll
        for (int m = 0; m < 16; ++m) {        // h=1: DPP quad_perm xor1, no twiddle
            const float2 p = make_float2(dppf<0xB1>(z[m].x), dppf<0xB1>(z[m].y));
            z[m] = hi1 ? csub(p, z[m]) : cadd(z[m], p);
        }

        // ---- window + OLA: sample n0+m; .x -> frame a, .y -> frame b ----
        const int  base_a = (ta - T0) * HOP + n0;      // 16-aligned, may be <0
        const int  base_b = base_a + HOP;
        const bool da = (unsigned)base_a < OLALEN;
        const bool db = vb && ((unsigned)base_b < OLALEN);
        const int  pa = PIDX(base_a);
        const int  pb = PIDX(base_b);
        #pragma unroll
        for (int m = 0; m < 16; ++m) {
            const float2 uz = z[SL[m]];
            const float  w  = 0.5f * WSCALE * (1.f - (V.x * CWT[m] - V.y * SWT[m]));
            if (da) atomicAdd(&ola[pa + m], uz.x * w);
            if (db) atomicAdd(&ola[pb + m], uz.y * w);
        }
    }

    __syncthreads();

    // plain-store exclusive region (every out element written exactly once)
    const int ownRows = (TROWS - T0 < OWN) ? (TROWS - T0) : OWN;
    const int total   = ownRows * HOP;
    float* og = out + (size_t)b * OUTLEN + (size_t)T0 * HOP;
    for (int i = tid; i < total; i += NTHR)
        og[i] = ola[PIDX(i)];
}

extern "C" void kernel_launch(void* const* d_in, const int* in_sizes, int n_in,
                              void* d_out, int out_size, void* d_ws, size_t ws_size,
                              hipStream_t stream)
{
    const float2* stfts = reinterpret_cast<const float2*>(d_in[0]);
    float* out = reinterpret_cast<float*>(d_out);

    istft_rfft2<<<dim3(BATCH * NBLK), dim3(NTHR), 0, stream>>>(stfts, out);
}